// Round 1
// baseline (1929.063 us; speedup 1.0000x reference)
//
#include <hip/hip_runtime.h>

#define N_CELLS 10000
#define N_GENES 4000
#define CELL_F  2000
#define GENE_F  50
#define HID     256
#define LAT     64
#define NCLUST  20
#define N_EDGES 640000

// ---------------- tiled f32 GEMM: C = A@W (+bias) ----------------
// A (M,K) row-major, W (K,N) row-major, C (M,N) row-major.
template<bool ADD_BIAS>
__global__ __launch_bounds__(256)
void gemm_kernel(const float* __restrict__ A, const float* __restrict__ W,
                 const float* __restrict__ bias, float* __restrict__ C,
                 int M, int N, int K)
{
    __shared__ float As[16][65];   // [k][m], +1 pad to break write conflicts
    __shared__ float Bs[16][64];   // [k][n]
    const int tid = threadIdx.x;
    const int tx = tid & 15, ty = tid >> 4;
    const int row0 = blockIdx.y * 64;
    const int col0 = blockIdx.x * 64;
    float acc[4][4] = {};
    for (int kt = 0; kt < K; kt += 16) {
        for (int l = tid; l < 64 * 16; l += 256) {
            int r = l >> 4, c = l & 15;
            int gr = row0 + r, gc = kt + c;
            As[c][r] = (gr < M && gc < K) ? A[(size_t)gr * K + gc] : 0.0f;
        }
        for (int l = tid; l < 16 * 64; l += 256) {
            int r = l >> 6, c = l & 63;
            int gr = kt + r, gc = col0 + c;
            Bs[r][c] = (gr < K && gc < N) ? W[(size_t)gr * N + gc] : 0.0f;
        }
        __syncthreads();
        #pragma unroll
        for (int kk = 0; kk < 16; ++kk) {
            float a[4], b[4];
            #pragma unroll
            for (int i = 0; i < 4; ++i) a[i] = As[kk][ty * 4 + i];
            #pragma unroll
            for (int j = 0; j < 4; ++j) b[j] = Bs[kk][tx * 4 + j];
            #pragma unroll
            for (int i = 0; i < 4; ++i)
                #pragma unroll
                for (int j = 0; j < 4; ++j)
                    acc[i][j] += a[i] * b[j];
        }
        __syncthreads();
    }
    #pragma unroll
    for (int i = 0; i < 4; ++i) {
        int r = row0 + ty * 4 + i;
        if (r >= M) continue;
        #pragma unroll
        for (int j = 0; j < 4; ++j) {
            int c = col0 + tx * 4 + j;
            if (c < N) C[(size_t)r * N + c] = acc[i][j] + (ADD_BIAS ? bias[c] : 0.0f);
        }
    }
}

// ---------------- CSR construction ----------------
__global__ void count_kernel(const int* __restrict__ er, const int* __restrict__ ec,
                             int* cnt_c, int* cnt_g)
{
    int e = blockIdx.x * blockDim.x + threadIdx.x;
    if (e < N_EDGES) {
        atomicAdd(&cnt_c[er[e]], 1);
        atomicAdd(&cnt_g[ec[e]], 1);
    }
}

__global__ __launch_bounds__(1024)
void scan_kernel(const int* __restrict__ cnt, int* __restrict__ ptr, int n)
{
    __shared__ int part[1024];
    int t = threadIdx.x;
    int chunk = (n + 1023) / 1024;
    int lo = t * chunk, hi = min(lo + chunk, n);
    int s = 0;
    for (int i = lo; i < hi; ++i) s += cnt[i];
    part[t] = s;
    __syncthreads();
    if (t == 0) {
        int run = 0;
        for (int i = 0; i < 1024; ++i) { int tmp = part[i]; part[i] = run; run += tmp; }
        ptr[n] = run;
    }
    __syncthreads();
    int run = part[t];
    for (int i = lo; i < hi; ++i) { ptr[i] = run; run += cnt[i]; }
}

__global__ void copy_int_kernel(const int* __restrict__ src, int* __restrict__ dst, int n)
{
    int i = blockIdx.x * blockDim.x + threadIdx.x;
    if (i < n) dst[i] = src[i];
}

__global__ void scatter_kernel(const int* __restrict__ er, const int* __restrict__ ec,
                               const float* __restrict__ ev,
                               int* cur_c, int* cur_g,
                               int* __restrict__ ci, float* __restrict__ cv,
                               int* __restrict__ gi, float* __restrict__ gv)
{
    int e = blockIdx.x * blockDim.x + threadIdx.x;
    if (e < N_EDGES) {
        int r = er[e], c = ec[e];
        float v = ev[e];
        int pc = atomicAdd(&cur_c[r], 1);
        ci[pc] = c; cv[pc] = v;
        int pg = atomicAdd(&cur_g[c], 1);
        gi[pg] = r; gv[pg] = v;
    }
}

// ---------------- fused segment-sum + residual + biases + relu ----------------
// out[r,:] = relu(pre[r,:] + sum_e val[e]*src[nbr[e],:] + b1 + b2)
__global__ __launch_bounds__(256)
void agg_kernel(const int* __restrict__ ptr, const int* __restrict__ nbr,
                const float* __restrict__ val, const float* __restrict__ src,
                const float* __restrict__ pre, const float* __restrict__ b1,
                const float* __restrict__ b2, float* __restrict__ out)
{
    __shared__ int   sj[256];
    __shared__ float sv[256];
    int r = blockIdx.x;
    int d = threadIdx.x;
    int s = ptr[r], e = ptr[r + 1];
    float acc = 0.0f;
    for (int base = s; base < e; base += 256) {
        int n = min(256, e - base);
        __syncthreads();
        if (d < n) { sj[d] = nbr[base + d]; sv[d] = val[base + d]; }
        __syncthreads();
        for (int i = 0; i < n; ++i)
            acc += sv[i] * src[(size_t)sj[i] * HID + d];
    }
    float x = pre[(size_t)r * HID + d] + acc + b1[d] + b2[d];
    out[(size_t)r * HID + d] = fmaxf(x, 0.0f);
}

// ---------------- decoder: out = z@w + b, K=64 ----------------
// z (M,64), w (64,N), out (M,N). Block: 256 cols x 32 rows.
__global__ __launch_bounds__(256)
void decoder_kernel(const float* __restrict__ z, const float* __restrict__ w,
                    const float* __restrict__ bias, float* __restrict__ out,
                    int M, int N)
{
    __shared__ float zs[32][64];
    int tid = threadIdx.x;
    int col = blockIdx.x * 256 + tid;
    int r0 = blockIdx.y * 32;
    for (int l = tid; l < 32 * 64; l += 256) {
        int rr = l >> 6, kk = l & 63;
        int gr = r0 + rr;
        zs[rr][kk] = (gr < M) ? z[(size_t)gr * 64 + kk] : 0.0f;
    }
    __syncthreads();
    if (col >= N) return;
    float acc[32] = {};
    for (int k = 0; k < 64; ++k) {
        float wv = w[(size_t)k * N + col];
        #pragma unroll
        for (int c = 0; c < 32; ++c) acc[c] += zs[c][k] * wv;
    }
    float bv = bias[col];
    #pragma unroll
    for (int c = 0; c < 32; ++c) {
        int r = r0 + c;
        if (r < M) out[(size_t)r * N + col] = acc[c] + bv;
    }
}

// ---------------- Student-t cluster assignment (ALPHA=1) ----------------
__global__ __launch_bounds__(256)
void q_kernel(const float* __restrict__ z, const float* __restrict__ centers,
              float* __restrict__ q)
{
    __shared__ float cs[NCLUST * LAT];
    int tid = threadIdx.x;
    for (int l = tid; l < NCLUST * LAT; l += 256) cs[l] = centers[l];
    __syncthreads();
    int c = blockIdx.x * 256 + tid;
    if (c >= N_CELLS) return;
    float zr[LAT];
    #pragma unroll
    for (int k = 0; k < LAT; ++k) zr[k] = z[(size_t)c * LAT + k];
    float num[NCLUST];
    float denom = 0.0f;
    for (int j = 0; j < NCLUST; ++j) {
        float d = 0.0f;
        #pragma unroll
        for (int k = 0; k < LAT; ++k) {
            float t = zr[k] - cs[j * LAT + k];
            d += t * t;
        }
        float n = 1.0f / (1.0f + d);   // (1 + d/alpha)^(-(alpha+1)/2), alpha=1
        num[j] = n;
        denom += n;
    }
    float inv = 1.0f / denom;
    for (int j = 0; j < NCLUST; ++j) q[(size_t)c * NCLUST + j] = num[j] * inv;
}

extern "C" void kernel_launch(void* const* d_in, const int* in_sizes, int n_in,
                              void* d_out, int out_size, void* d_ws, size_t ws_size,
                              hipStream_t stream)
{
    const float* cell_x  = (const float*)d_in[0];
    const float* gene_x  = (const float*)d_in[1];
    const int*   er      = (const int*)d_in[2];
    const int*   ec      = (const int*)d_in[3];
    const float* ev      = (const float*)d_in[4];
    const float* l0_cs_w = (const float*)d_in[5];  const float* l0_cs_b = (const float*)d_in[6];
    const float* l0_cn_w = (const float*)d_in[7];  const float* l0_cn_b = (const float*)d_in[8];
    const float* l0_gs_w = (const float*)d_in[9];  const float* l0_gs_b = (const float*)d_in[10];
    const float* l0_gn_w = (const float*)d_in[11]; const float* l0_gn_b = (const float*)d_in[12];
    const float* l1_cs_w = (const float*)d_in[13]; const float* l1_cs_b = (const float*)d_in[14];
    const float* l1_cn_w = (const float*)d_in[15]; const float* l1_cn_b = (const float*)d_in[16];
    const float* l1_gs_w = (const float*)d_in[17]; const float* l1_gs_b = (const float*)d_in[18];
    const float* l1_gn_w = (const float*)d_in[19]; const float* l1_gn_b = (const float*)d_in[20];
    const float* cl_w = (const float*)d_in[21]; const float* cl_b = (const float*)d_in[22];
    const float* gl_w = (const float*)d_in[23]; const float* gl_b = (const float*)d_in[24];
    const float* cd_w = (const float*)d_in[25]; const float* cd_b = (const float*)d_in[26];
    const float* gd_w = (const float*)d_in[27]; const float* gd_b = (const float*)d_in[28];
    const float* centers = (const float*)d_in[29];

    float* out = (float*)d_out;
    float* z_cells    = out;                       // 10000*64
    float* z_genes    = out + 640000;              // 4000*64
    float* cell_recon = out + 896000;              // 10000*4000
    float* gene_recon = out + 40896000;            // 4000*10000
    float* q          = out + 80896000;            // 10000*20

    // workspace arena (~68 MB)
    char* wsp = (char*)d_ws;
    float* pre_c = (float*)wsp; wsp += (size_t)N_CELLS * HID * 4;  // pre_cs / pre_cs1
    float* t_c   = (float*)wsp; wsp += (size_t)N_CELLS * HID * 4;  // t_c / u_c
    float* pre_g = (float*)wsp; wsp += (size_t)N_GENES * HID * 4;  // pre_gs / pre_gs1
    float* t_g   = (float*)wsp; wsp += (size_t)N_GENES * HID * 4;  // t_g / u_g
    float* c1    = (float*)wsp; wsp += (size_t)N_CELLS * HID * 4;
    float* g1    = (float*)wsp; wsp += (size_t)N_GENES * HID * 4;
    float* c2    = (float*)wsp; wsp += (size_t)N_CELLS * HID * 4;
    float* g2    = (float*)wsp; wsp += (size_t)N_GENES * HID * 4;
    int* cnt_c = (int*)wsp; wsp += (size_t)N_CELLS * 4;
    int* cnt_g = (int*)wsp; wsp += (size_t)N_GENES * 4;
    int* ptr_c = (int*)wsp; wsp += (size_t)(N_CELLS + 1) * 4;
    int* ptr_g = (int*)wsp; wsp += (size_t)(N_GENES + 1) * 4;
    int* cur_c = (int*)wsp; wsp += (size_t)N_CELLS * 4;
    int* cur_g = (int*)wsp; wsp += (size_t)N_GENES * 4;
    int*   ci = (int*)wsp;   wsp += (size_t)N_EDGES * 4;  // gene idx per cell-sorted edge
    float* cv = (float*)wsp; wsp += (size_t)N_EDGES * 4;
    int*   gi = (int*)wsp;   wsp += (size_t)N_EDGES * 4;  // cell idx per gene-sorted edge
    float* gv = (float*)wsp; wsp += (size_t)N_EDGES * 4;

    // ---- CSR build (cnt_c and cnt_g are contiguous) ----
    hipMemsetAsync(cnt_c, 0, (size_t)(N_CELLS + N_GENES) * 4, stream);
    count_kernel<<<(N_EDGES + 255) / 256, 256, 0, stream>>>(er, ec, cnt_c, cnt_g);
    scan_kernel<<<1, 1024, 0, stream>>>(cnt_c, ptr_c, N_CELLS);
    scan_kernel<<<1, 1024, 0, stream>>>(cnt_g, ptr_g, N_GENES);
    copy_int_kernel<<<(N_CELLS + 255) / 256, 256, 0, stream>>>(ptr_c, cur_c, N_CELLS);
    copy_int_kernel<<<(N_GENES + 255) / 256, 256, 0, stream>>>(ptr_g, cur_g, N_GENES);
    scatter_kernel<<<(N_EDGES + 255) / 256, 256, 0, stream>>>(er, ec, ev, cur_c, cur_g,
                                                              ci, cv, gi, gv);

    // ---- layer 0 dense projections (weights pushed before sparse op) ----
    gemm_kernel<false><<<dim3(HID / 64, (N_CELLS + 63) / 64), 256, 0, stream>>>(
        cell_x, l0_cs_w, nullptr, pre_c, N_CELLS, HID, CELL_F);
    gemm_kernel<false><<<dim3(HID / 64, (N_CELLS + 63) / 64), 256, 0, stream>>>(
        cell_x, l0_gn_w, nullptr, t_c, N_CELLS, HID, CELL_F);
    gemm_kernel<false><<<dim3(HID / 64, (N_GENES + 63) / 64), 256, 0, stream>>>(
        gene_x, l0_gs_w, nullptr, pre_g, N_GENES, HID, GENE_F);
    gemm_kernel<false><<<dim3(HID / 64, (N_GENES + 63) / 64), 256, 0, stream>>>(
        gene_x, l0_cn_w, nullptr, t_g, N_GENES, HID, GENE_F);

    // c1 = relu(pre_c + A@t_g + b), g1 = relu(pre_g + A^T@t_c + b)
    agg_kernel<<<N_CELLS, 256, 0, stream>>>(ptr_c, ci, cv, t_g, pre_c, l0_cs_b, l0_cn_b, c1);
    agg_kernel<<<N_GENES, 256, 0, stream>>>(ptr_g, gi, gv, t_c, pre_g, l0_gs_b, l0_gn_b, g1);

    // ---- layer 1 (reuse buffers) ----
    gemm_kernel<false><<<dim3(HID / 64, (N_CELLS + 63) / 64), 256, 0, stream>>>(
        c1, l1_cs_w, nullptr, pre_c, N_CELLS, HID, HID);
    gemm_kernel<false><<<dim3(HID / 64, (N_CELLS + 63) / 64), 256, 0, stream>>>(
        c1, l1_gn_w, nullptr, t_c, N_CELLS, HID, HID);
    gemm_kernel<false><<<dim3(HID / 64, (N_GENES + 63) / 64), 256, 0, stream>>>(
        g1, l1_gs_w, nullptr, pre_g, N_GENES, HID, HID);
    gemm_kernel<false><<<dim3(HID / 64, (N_GENES + 63) / 64), 256, 0, stream>>>(
        g1, l1_cn_w, nullptr, t_g, N_GENES, HID, HID);

    agg_kernel<<<N_CELLS, 256, 0, stream>>>(ptr_c, ci, cv, t_g, pre_c, l1_cs_b, l1_cn_b, c2);
    agg_kernel<<<N_GENES, 256, 0, stream>>>(ptr_g, gi, gv, t_c, pre_g, l1_gs_b, l1_gn_b, g2);

    // ---- latent heads ----
    gemm_kernel<true><<<dim3(1, (N_CELLS + 63) / 64), 256, 0, stream>>>(
        c2, cl_w, cl_b, z_cells, N_CELLS, LAT, HID);
    gemm_kernel<true><<<dim3(1, (N_GENES + 63) / 64), 256, 0, stream>>>(
        g2, gl_w, gl_b, z_genes, N_GENES, LAT, HID);

    // ---- decoders ----
    decoder_kernel<<<dim3((N_GENES + 255) / 256, (N_CELLS + 31) / 32), 256, 0, stream>>>(
        z_cells, cd_w, cd_b, cell_recon, N_CELLS, N_GENES);
    decoder_kernel<<<dim3((N_CELLS + 255) / 256, (N_GENES + 31) / 32), 256, 0, stream>>>(
        z_genes, gd_w, gd_b, gene_recon, N_GENES, N_CELLS);

    // ---- DEC soft assignment ----
    q_kernel<<<(N_CELLS + 255) / 256, 256, 0, stream>>>(z_cells, centers, q);
}

// Round 3
// 618.339 us; speedup vs baseline: 3.1197x; 3.1197x over previous
//
#include <hip/hip_runtime.h>

#define N_CELLS 10000
#define N_GENES 4000
#define CELL_F  2000
#define GENE_F  50
#define HID     256
#define LAT     64
#define NCLUST  20
#define N_EDGES 640000

typedef __attribute__((ext_vector_type(8))) short    bf16x8;
typedef __attribute__((ext_vector_type(8))) unsigned short u16x8;
typedef __attribute__((ext_vector_type(4))) float    f32x4;

__device__ __forceinline__ unsigned short f2bf(float f) {
    unsigned int u = __float_as_uint(f);
    unsigned int r = (u + 0x7FFFu + ((u >> 16) & 1u)) >> 16;
    return (unsigned short)r;
}
__device__ __forceinline__ float bf2f(unsigned short h) {
    return __uint_as_float(((unsigned int)h) << 16);
}

// ---------------- bf16 MFMA GEMM ----------------
// C(M,N) = A(M,K) @ BT(N,K)^T  [+bias]
// A: f32 or bf16(ushort) row-major, stride K. BT: bf16, rows padded to >= grid.x*64.
// Tile 64x64, BK=64, 4 waves (each: 16 rows x 64 cols via 4 col-fragments).
template<typename AT, bool BIAS, bool WF32, bool WBF>
__global__ __launch_bounds__(256)
void mfma_gemm(const AT* __restrict__ A, const unsigned short* __restrict__ BT,
               const float* __restrict__ bias, float* __restrict__ C,
               unsigned short* __restrict__ Cbf, int M, int N, int K)
{
    __shared__ __align__(16) unsigned short As[64][72];
    __shared__ __align__(16) unsigned short Bs[64][72];
    const int tid  = threadIdx.x;
    const int row0 = blockIdx.y * 64;
    const int col0 = blockIdx.x * 64;
    const int lane = tid & 63;
    const int w    = tid >> 6;
    const int cn   = lane & 15;
    const int rj   = lane >> 4;

    const bool avec = (sizeof(AT) == 2) ? ((K & 7) == 0) : ((K & 3) == 0);
    const bool bvec = ((K & 7) == 0);

    f32x4 acc[4] = {};

    for (int kt = 0; kt < K; kt += 64) {
        // 64x64 bf16 tile = 512 vec8 chunks; 8 chunks per row.
        // c in [0,512): r = c>>3 (row 0..63), p = c&7 (chunk 0..7).
        #pragma unroll
        for (int half = 0; half < 2; ++half) {
            int c = tid + half * 256;
            int r = c >> 3, p = c & 7;
            int gc = kt + p * 8;
            // ---- A tile ----
            {
                int gr = row0 + r;
                u16x8 v = {0, 0, 0, 0, 0, 0, 0, 0};
                if (gr < M) {
                    if constexpr (sizeof(AT) == 2) {
                        const unsigned short* src = (const unsigned short*)A + (size_t)gr * K + gc;
                        if (avec && gc + 8 <= K) {
                            v = *(const u16x8*)src;
                        } else {
                            #pragma unroll
                            for (int j = 0; j < 8; ++j) if (gc + j < K) v[j] = src[j];
                        }
                    } else {
                        const float* src = (const float*)A + (size_t)gr * K + gc;
                        if (avec && gc + 8 <= K) {
                            float4 f0 = *(const float4*)src;
                            float4 f1 = *(const float4*)(src + 4);
                            v[0] = f2bf(f0.x); v[1] = f2bf(f0.y); v[2] = f2bf(f0.z); v[3] = f2bf(f0.w);
                            v[4] = f2bf(f1.x); v[5] = f2bf(f1.y); v[6] = f2bf(f1.z); v[7] = f2bf(f1.w);
                        } else {
                            #pragma unroll
                            for (int j = 0; j < 8; ++j) if (gc + j < K) v[j] = f2bf(src[j]);
                        }
                    }
                }
                *(u16x8*)&As[r][p * 8] = v;
            }
            // ---- B tile (BT rows are alloc-padded, no row guard needed) ----
            {
                int gn = col0 + r;
                const unsigned short* src = BT + (size_t)gn * K + gc;
                u16x8 v = {0, 0, 0, 0, 0, 0, 0, 0};
                if (bvec && gc + 8 <= K) {
                    v = *(const u16x8*)src;
                } else {
                    #pragma unroll
                    for (int j = 0; j < 8; ++j) if (gc + j < K) v[j] = src[j];
                }
                *(u16x8*)&Bs[r][p * 8] = v;
            }
        }
        __syncthreads();
        #pragma unroll
        for (int kk = 0; kk < 64; kk += 32) {
            bf16x8 a = *(const bf16x8*)&As[w * 16 + cn][kk + rj * 8];
            #pragma unroll
            for (int f = 0; f < 4; ++f) {
                bf16x8 b = *(const bf16x8*)&Bs[f * 16 + cn][kk + rj * 8];
                acc[f] = __builtin_amdgcn_mfma_f32_16x16x32_bf16(a, b, acc[f], 0, 0, 0);
            }
        }
        __syncthreads();
    }

    // ---- epilogue: D col = lane&15, row = (lane>>4)*4 + reg  [m89] ----
    #pragma unroll
    for (int f = 0; f < 4; ++f) {
        int col = col0 + f * 16 + cn;
        if (col >= N) continue;
        float bv = BIAS ? bias[col] : 0.0f;
        #pragma unroll
        for (int j = 0; j < 4; ++j) {
            int r = row0 + w * 16 + rj * 4 + j;
            if (r < M) {
                float val = acc[f][j] + bv;
                if (WF32) C[(size_t)r * N + col] = val;
                if (WBF)  Cbf[(size_t)r * N + col] = f2bf(val);
            }
        }
    }
}

// ---------------- weight pack: BT[n][k] = [W1 | W2](k, n), bf16 ----------------
__global__ void pack_bt(const float* __restrict__ W1, const float* __restrict__ W2,
                        unsigned short* __restrict__ BT, int K, int N1, int N2, int Np)
{
    int i = blockIdx.x * blockDim.x + threadIdx.x;
    if (i >= Np * K) return;
    int n = i / K, k = i - n * K;
    float v = 0.0f;
    if (n < N1) v = W1[(size_t)k * N1 + n];
    else if (n < N1 + N2) v = W2[(size_t)k * N2 + (n - N1)];
    BT[i] = f2bf(v);
}

// ---------------- CSR construction ----------------
__global__ void count_kernel(const int* __restrict__ er, const int* __restrict__ ec,
                             int* cnt_c, int* cnt_g)
{
    int e = blockIdx.x * blockDim.x + threadIdx.x;
    if (e < N_EDGES) {
        atomicAdd(&cnt_c[er[e]], 1);
        atomicAdd(&cnt_g[ec[e]], 1);
    }
}

__global__ __launch_bounds__(1024)
void scan_kernel(const int* __restrict__ cnt, int* __restrict__ ptr, int n)
{
    __shared__ int part[1024];
    int t = threadIdx.x;
    int chunk = (n + 1023) / 1024;
    int lo = t * chunk, hi = min(lo + chunk, n);
    int s = 0;
    for (int i = lo; i < hi; ++i) s += cnt[i];
    part[t] = s;
    __syncthreads();
    if (t == 0) {
        int run = 0;
        for (int i = 0; i < 1024; ++i) { int tmp = part[i]; part[i] = run; run += tmp; }
        ptr[n] = run;
    }
    __syncthreads();
    int run = part[t];
    for (int i = lo; i < hi; ++i) { ptr[i] = run; run += cnt[i]; }
}

__global__ void copy_int_kernel(const int* __restrict__ src, int* __restrict__ dst, int n)
{
    int i = blockIdx.x * blockDim.x + threadIdx.x;
    if (i < n) dst[i] = src[i];
}

__global__ void scatter_kernel(const int* __restrict__ er, const int* __restrict__ ec,
                               const float* __restrict__ ev,
                               int* cur_c, int* cur_g,
                               int* __restrict__ ci, float* __restrict__ cv,
                               int* __restrict__ gi, float* __restrict__ gv)
{
    int e = blockIdx.x * blockDim.x + threadIdx.x;
    if (e < N_EDGES) {
        int r = er[e], c = ec[e];
        float v = ev[e];
        int pc = atomicAdd(&cur_c[r], 1);
        ci[pc] = c; cv[pc] = v;
        int pg = atomicAdd(&cur_g[c], 1);
        gi[pg] = r; gv[pg] = v;
    }
}

// ---- fused segment-sum + residual + biases + relu; bf16 in/out, f32 math ----
// out[r,:] = relu(pre[r,0:256] + sum_e val[e]*src[nbr[e],256:512] + b1 + b2)
__global__ __launch_bounds__(256)
void agg_kernel(const int* __restrict__ ptr, const int* __restrict__ nbr,
                const float* __restrict__ val,
                const unsigned short* __restrict__ srcbf,  // stride 512, cols 256..511
                const unsigned short* __restrict__ prebf,  // stride 512, cols 0..255
                const float* __restrict__ b1, const float* __restrict__ b2,
                unsigned short* __restrict__ outbf)        // stride 256
{
    __shared__ int   sj[256];
    __shared__ float sv[256];
    int r = blockIdx.x;
    int d = threadIdx.x;
    int s = ptr[r], e = ptr[r + 1];
    float acc = 0.0f;
    for (int base = s; base < e; base += 256) {
        int n = min(256, e - base);
        __syncthreads();
        if (d < n) { sj[d] = nbr[base + d]; sv[d] = val[base + d]; }
        __syncthreads();
        for (int i = 0; i < n; ++i)
            acc += sv[i] * bf2f(srcbf[(size_t)sj[i] * 512 + 256 + d]);
    }
    float x = bf2f(prebf[(size_t)r * 512 + d]) + acc + b1[d] + b2[d];
    outbf[(size_t)r * 256 + d] = f2bf(fmaxf(x, 0.0f));
}

// ---------------- Student-t cluster assignment (ALPHA=1) ----------------
__global__ __launch_bounds__(256)
void q_kernel(const float* __restrict__ z, const float* __restrict__ centers,
              float* __restrict__ q)
{
    __shared__ float cs[NCLUST * LAT];
    int tid = threadIdx.x;
    for (int l = tid; l < NCLUST * LAT; l += 256) cs[l] = centers[l];
    __syncthreads();
    int c = blockIdx.x * 256 + tid;
    if (c >= N_CELLS) return;
    float zr[LAT];
    #pragma unroll
    for (int k = 0; k < LAT; ++k) zr[k] = z[(size_t)c * LAT + k];
    float num[NCLUST];
    float denom = 0.0f;
    for (int j = 0; j < NCLUST; ++j) {
        float d = 0.0f;
        #pragma unroll
        for (int k = 0; k < LAT; ++k) {
            float t = zr[k] - cs[j * LAT + k];
            d += t * t;
        }
        float n = 1.0f / (1.0f + d);
        num[j] = n;
        denom += n;
    }
    float inv = 1.0f / denom;
    for (int j = 0; j < NCLUST; ++j) q[(size_t)c * NCLUST + j] = num[j] * inv;
}

extern "C" void kernel_launch(void* const* d_in, const int* in_sizes, int n_in,
                              void* d_out, int out_size, void* d_ws, size_t ws_size,
                              hipStream_t stream)
{
    const float* cell_x  = (const float*)d_in[0];
    const float* gene_x  = (const float*)d_in[1];
    const int*   er      = (const int*)d_in[2];
    const int*   ec      = (const int*)d_in[3];
    const float* ev      = (const float*)d_in[4];
    const float* l0_cs_w = (const float*)d_in[5];  const float* l0_cs_b = (const float*)d_in[6];
    const float* l0_cn_w = (const float*)d_in[7];  const float* l0_cn_b = (const float*)d_in[8];
    const float* l0_gs_w = (const float*)d_in[9];  const float* l0_gs_b = (const float*)d_in[10];
    const float* l0_gn_w = (const float*)d_in[11]; const float* l0_gn_b = (const float*)d_in[12];
    const float* l1_cs_w = (const float*)d_in[13]; const float* l1_cs_b = (const float*)d_in[14];
    const float* l1_cn_w = (const float*)d_in[15]; const float* l1_cn_b = (const float*)d_in[16];
    const float* l1_gs_w = (const float*)d_in[17]; const float* l1_gs_b = (const float*)d_in[18];
    const float* l1_gn_w = (const float*)d_in[19]; const float* l1_gn_b = (const float*)d_in[20];
    const float* cl_w = (const float*)d_in[21]; const float* cl_b = (const float*)d_in[22];
    const float* gl_w = (const float*)d_in[23]; const float* gl_b = (const float*)d_in[24];
    const float* cd_w = (const float*)d_in[25]; const float* cd_b = (const float*)d_in[26];
    const float* gd_w = (const float*)d_in[27]; const float* gd_b = (const float*)d_in[28];
    const float* centers = (const float*)d_in[29];

    float* out = (float*)d_out;
    float* z_cells    = out;                       // 10000*64
    float* z_genes    = out + 640000;              // 4000*64
    float* cell_recon = out + 896000;              // 10000*4000
    float* gene_recon = out + 40896000;            // 4000*10000
    float* q          = out + 80896000;            // 10000*20

    // ---- workspace arena (~46 MB, 256B-aligned blocks) ----
    char* wsp = (char*)d_ws;
    auto alloc = [&](size_t bytes) -> void* {
        void* p = (void*)wsp;
        wsp += (bytes + 255) & ~(size_t)255;
        return p;
    };
    unsigned short* pre_c_bf = (unsigned short*)alloc((size_t)N_CELLS * 512 * 2);
    unsigned short* pre_g_bf = (unsigned short*)alloc((size_t)N_GENES * 512 * 2);
    unsigned short* c1_bf    = (unsigned short*)alloc((size_t)N_CELLS * 256 * 2);
    unsigned short* g1_bf    = (unsigned short*)alloc((size_t)N_GENES * 256 * 2);
    unsigned short* c2_bf    = (unsigned short*)alloc((size_t)N_CELLS * 256 * 2);
    unsigned short* g2_bf    = (unsigned short*)alloc((size_t)N_GENES * 256 * 2);
    unsigned short* zc_bf    = (unsigned short*)alloc((size_t)N_CELLS * 64 * 2);
    unsigned short* zg_bf    = (unsigned short*)alloc((size_t)N_GENES * 64 * 2);
    unsigned short* W0cT = (unsigned short*)alloc((size_t)512 * CELL_F * 2);
    unsigned short* W0gT = (unsigned short*)alloc((size_t)512 * GENE_F * 2);
    unsigned short* W1cT = (unsigned short*)alloc((size_t)512 * HID * 2);
    unsigned short* W1gT = (unsigned short*)alloc((size_t)512 * HID * 2);
    unsigned short* WzcT = (unsigned short*)alloc((size_t)64 * HID * 2);
    unsigned short* WzgT = (unsigned short*)alloc((size_t)64 * HID * 2);
    unsigned short* WdcT = (unsigned short*)alloc((size_t)4032 * 64 * 2);
    unsigned short* WdgT = (unsigned short*)alloc((size_t)10048 * 64 * 2);
    int* cnt_c = (int*)alloc((size_t)(N_CELLS + N_GENES) * 4);   // cnt_c + cnt_g contiguous
    int* cnt_g = cnt_c + N_CELLS;
    int* ptr_c = (int*)alloc((size_t)(N_CELLS + 1) * 4);
    int* ptr_g = (int*)alloc((size_t)(N_GENES + 1) * 4);
    int* cur_c = (int*)alloc((size_t)N_CELLS * 4);
    int* cur_g = (int*)alloc((size_t)N_GENES * 4);
    int*   ci = (int*)alloc((size_t)N_EDGES * 4);
    float* cv = (float*)alloc((size_t)N_EDGES * 4);
    int*   gi = (int*)alloc((size_t)N_EDGES * 4);
    float* gv = (float*)alloc((size_t)N_EDGES * 4);

    // ---- CSR build ----
    hipMemsetAsync(cnt_c, 0, (size_t)(N_CELLS + N_GENES) * 4, stream);
    count_kernel<<<(N_EDGES + 255) / 256, 256, 0, stream>>>(er, ec, cnt_c, cnt_g);
    scan_kernel<<<1, 1024, 0, stream>>>(cnt_c, ptr_c, N_CELLS);
    scan_kernel<<<1, 1024, 0, stream>>>(cnt_g, ptr_g, N_GENES);
    copy_int_kernel<<<(N_CELLS + 255) / 256, 256, 0, stream>>>(ptr_c, cur_c, N_CELLS);
    copy_int_kernel<<<(N_GENES + 255) / 256, 256, 0, stream>>>(ptr_g, cur_g, N_GENES);
    scatter_kernel<<<(N_EDGES + 255) / 256, 256, 0, stream>>>(er, ec, ev, cur_c, cur_g,
                                                              ci, cv, gi, gv);

    // ---- weight packs (bf16, transposed, N-concat) ----
    auto packs = [&](const float* W1, const float* W2, unsigned short* BT,
                     int K, int N1, int N2, int Np) {
        pack_bt<<<(Np * K + 255) / 256, 256, 0, stream>>>(W1, W2, BT, K, N1, N2, Np);
    };
    packs(l0_cs_w, l0_gn_w, W0cT, CELL_F, HID, HID, 512);
    packs(l0_gs_w, l0_cn_w, W0gT, GENE_F, HID, HID, 512);
    packs(l1_cs_w, l1_gn_w, W1cT, HID, HID, HID, 512);
    packs(l1_gs_w, l1_cn_w, W1gT, HID, HID, HID, 512);
    packs(cl_w, nullptr, WzcT, HID, LAT, 0, 64);
    packs(gl_w, nullptr, WzgT, HID, LAT, 0, 64);
    packs(cd_w, nullptr, WdcT, LAT, N_GENES, 0, 4032);
    packs(gd_w, nullptr, WdgT, LAT, N_CELLS, 0, 10048);

    #define GRID(Mv, Nv) dim3(((Nv) + 63) / 64, ((Mv) + 63) / 64)

    // ---- layer 0: [self | neigh] projections ----
    mfma_gemm<float, false, false, true><<<GRID(N_CELLS, 512), 256, 0, stream>>>(
        cell_x, W0cT, nullptr, nullptr, pre_c_bf, N_CELLS, 512, CELL_F);
    mfma_gemm<float, false, false, true><<<GRID(N_GENES, 512), 256, 0, stream>>>(
        gene_x, W0gT, nullptr, nullptr, pre_g_bf, N_GENES, 512, GENE_F);

    agg_kernel<<<N_CELLS, 256, 0, stream>>>(ptr_c, ci, cv, pre_g_bf, pre_c_bf,
                                            l0_cs_b, l0_cn_b, c1_bf);
    agg_kernel<<<N_GENES, 256, 0, stream>>>(ptr_g, gi, gv, pre_c_bf, pre_g_bf,
                                            l0_gs_b, l0_gn_b, g1_bf);

    // ---- layer 1 ----
    mfma_gemm<unsigned short, false, false, true><<<GRID(N_CELLS, 512), 256, 0, stream>>>(
        c1_bf, W1cT, nullptr, nullptr, pre_c_bf, N_CELLS, 512, HID);
    mfma_gemm<unsigned short, false, false, true><<<GRID(N_GENES, 512), 256, 0, stream>>>(
        g1_bf, W1gT, nullptr, nullptr, pre_g_bf, N_GENES, 512, HID);

    agg_kernel<<<N_CELLS, 256, 0, stream>>>(ptr_c, ci, cv, pre_g_bf, pre_c_bf,
                                            l1_cs_b, l1_cn_b, c2_bf);
    agg_kernel<<<N_GENES, 256, 0, stream>>>(ptr_g, gi, gv, pre_c_bf, pre_g_bf,
                                            l1_gs_b, l1_gn_b, g2_bf);

    // ---- latent heads (f32 to d_out + bf16 for decoders) ----
    mfma_gemm<unsigned short, true, true, true><<<GRID(N_CELLS, LAT), 256, 0, stream>>>(
        c2_bf, WzcT, cl_b, z_cells, zc_bf, N_CELLS, LAT, HID);
    mfma_gemm<unsigned short, true, true, true><<<GRID(N_GENES, LAT), 256, 0, stream>>>(
        g2_bf, WzgT, gl_b, z_genes, zg_bf, N_GENES, LAT, HID);

    // ---- decoders ----
    mfma_gemm<unsigned short, true, true, false><<<GRID(N_CELLS, N_GENES), 256, 0, stream>>>(
        zc_bf, WdcT, cd_b, cell_recon, nullptr, N_CELLS, N_GENES, LAT);
    mfma_gemm<unsigned short, true, true, false><<<GRID(N_GENES, N_CELLS), 256, 0, stream>>>(
        zg_bf, WdgT, gd_b, gene_recon, nullptr, N_GENES, N_CELLS, LAT);

    // ---- DEC soft assignment ----
    q_kernel<<<(N_CELLS + 255) / 256, 256, 0, stream>>>(z_cells, centers, q);
}